// Round 1
// baseline (388.344 us; speedup 1.0000x reference)
//
#include <hip/hip_runtime.h>

typedef unsigned short u16;
typedef __bf16 bf16x8 __attribute__((ext_vector_type(8)));
typedef float f32x4 __attribute__((ext_vector_type(4)));
typedef u16 u16x4 __attribute__((ext_vector_type(4)));

// ---------- helpers ----------
__device__ __forceinline__ u16 f2bf(float f) {
  unsigned u = __float_as_uint(f);
  u += 0x7fffu + ((u >> 16) & 1u);   // round-to-nearest-even
  return (u16)(u >> 16);
}

__device__ __forceinline__ void gload16(const u16* g, u16* l) {
  // 16B per lane, LDS dest = wave-uniform base + lane*16
  __builtin_amdgcn_global_load_lds((__attribute__((address_space(1))) void*)g,
                                   (__attribute__((address_space(3))) void*)l,
                                   16, 0, 0);
}

// ---------- fp32 -> bf16 elementwise ----------
__global__ __launch_bounds__(256) void cvt_f32_bf16(const float* __restrict__ in,
                                                    u16* __restrict__ out, int n4) {
  int i = blockIdx.x * 256 + threadIdx.x;
  if (i >= n4) return;
  float4 v = ((const float4*)in)[i];
  u16x4 o = { f2bf(v.x), f2bf(v.y), f2bf(v.z), f2bf(v.w) };
  ((u16x4*)out)[i] = o;
}

// ---------- fp32 [R][C] -> bf16 [C][R] tiled transpose ----------
__global__ __launch_bounds__(256) void transpose_cvt(const float* __restrict__ in,
                                                     u16* __restrict__ out, int R, int C) {
  __shared__ float tile[32][33];
  int c0 = blockIdx.x * 32, r0 = blockIdx.y * 32;
  int tx = threadIdx.x & 31, ty = threadIdx.x >> 5;  // 32 x 8
#pragma unroll
  for (int i = 0; i < 32; i += 8)
    tile[ty + i][tx] = in[(size_t)(r0 + ty + i) * C + c0 + tx];
  __syncthreads();
#pragma unroll
  for (int i = 0; i < 32; i += 8)
    out[(size_t)(c0 + ty + i) * R + r0 + tx] = f2bf(tile[tx][ty + i]);
}

// ---------- 128x128 bf16 GEMM, B pre-transposed [N][K] ----------
// EPI==0: qkv epilogue (bias, q-scale, scatter to q/k/v_t).  EPI==1: proj (bias, fp32 out).
template <int EPI>
__global__ __launch_bounds__(256) void gemm_bt(const u16* __restrict__ A,
                                               const u16* __restrict__ Bt, int K,
                                               const float* __restrict__ bias,
                                               float* __restrict__ outF,
                                               u16* __restrict__ qb, u16* __restrict__ kb,
                                               u16* __restrict__ vtb) {
  __shared__ __align__(16) u16 As[128 * 32];
  __shared__ __align__(16) u16 Bs[128 * 32];
  const int tid = threadIdx.x;
  const int w = tid >> 6, lane = tid & 63, quad = lane >> 4, l16 = lane & 15;
  const int wm = w >> 1, wn = w & 1;
  const int tm = blockIdx.y * 128, tn = blockIdx.x * 128;

  f32x4 acc[4][4] = {};

  const int ra = lane >> 2;        // row within 16-row chunk
  const int ca = (lane & 3) * 8;   // k offset (elements)
  const u16* gA0 = A + (size_t)(tm + w * 16 + ra) * K + ca;
  const u16* gA1 = A + (size_t)(tm + (w + 4) * 16 + ra) * K + ca;
  const u16* gB0 = Bt + (size_t)(tn + w * 16 + ra) * K + ca;
  const u16* gB1 = Bt + (size_t)(tn + (w + 4) * 16 + ra) * K + ca;
  u16* lA0 = &As[(w * 16) * 32];
  u16* lA1 = &As[((w + 4) * 16) * 32];
  u16* lB0 = &Bs[(w * 16) * 32];
  u16* lB1 = &Bs[((w + 4) * 16) * 32];

  for (int k0 = 0; k0 < K; k0 += 32) {
    gload16(gA0 + k0, lA0);
    gload16(gA1 + k0, lA1);
    gload16(gB0 + k0, lB0);
    gload16(gB1 + k0, lB1);
    __syncthreads();  // drains vmcnt -> LDS staged
    bf16x8 af[4], bfr[4];
#pragma unroll
    for (int mt = 0; mt < 4; ++mt)
      af[mt] = *(const bf16x8*)&As[(wm * 64 + mt * 16 + l16) * 32 + quad * 8];
#pragma unroll
    for (int nt = 0; nt < 4; ++nt)
      bfr[nt] = *(const bf16x8*)&Bs[(wn * 64 + nt * 16 + l16) * 32 + quad * 8];
#pragma unroll
    for (int mt = 0; mt < 4; ++mt)
#pragma unroll
      for (int nt = 0; nt < 4; ++nt)
        acc[mt][nt] = __builtin_amdgcn_mfma_f32_16x16x32_bf16(af[mt], bfr[nt], acc[mt][nt], 0, 0, 0);
    __syncthreads();  // LDS reads done before next staging
  }

#pragma unroll
  for (int mt = 0; mt < 4; ++mt) {
#pragma unroll
    for (int nt = 0; nt < 4; ++nt) {
#pragma unroll
      for (int r = 0; r < 4; ++r) {
        int row = tm + wm * 64 + mt * 16 + quad * 4 + r;  // C/D: row=(lane>>4)*4+reg
        int col = tn + wn * 64 + nt * 16 + l16;           // C/D: col=lane&15
        float v = acc[mt][nt][r] + bias[col];
        if (EPI == 0) {
          int which = col >> 10, d = col & 1023, h = d >> 6, dd = d & 63;
          int b = row >> 11, t = row & 2047;
          int bh = (b << 4) + h;
          if (which == 0)
            qb[((size_t)bh * 2048 + t) * 64 + dd] = f2bf(v * 0.125f);  // fold 1/sqrt(64)
          else if (which == 1)
            kb[((size_t)bh * 2048 + t) * 64 + dd] = f2bf(v);
          else
            vtb[((size_t)bh * 64 + dd) * 2048 + t] = f2bf(v);  // V transposed [dh][T]
        } else {
          outF[(size_t)row * 1024 + col] = v;
        }
      }
    }
  }
}

// ---------- causal flash attention: block = (64 q-rows) x (b,h) ----------
__global__ __launch_bounds__(256) void flash_attn(const u16* __restrict__ qb,
                                                  const u16* __restrict__ kb,
                                                  const u16* __restrict__ vtb,
                                                  u16* __restrict__ ao) {
  const int T = 2048;
  int w = threadIdx.x >> 6, lane = threadIdx.x & 63;
  int quad = lane >> 4, l16 = lane & 15;
  int qtile = blockIdx.x, bh = blockIdx.y;
  int b = bh >> 4, h = bh & 15;
  int qrow0 = qtile * 64 + w * 16;  // this wave's 16-row stripe
  int qr = qrow0 + l16;
  const size_t qkbase = (size_t)bh * T * 64;

  bf16x8 qf0 = *(const bf16x8*)(qb + qkbase + (size_t)qr * 64 + quad * 8);
  bf16x8 qf1 = *(const bf16x8*)(qb + qkbase + (size_t)qr * 64 + 32 + quad * 8);

  float m_s[4], l_s[4];
  f32x4 o[4] = {};
#pragma unroll
  for (int r = 0; r < 4; ++r) { m_s[r] = -1e30f; l_s[r] = 0.f; }

  __shared__ __align__(16) u16 pl[4][16][40];  // per-wave P tile, +8 pad
  int nkt = qtile * 2 + 2;  // uniform across waves -> __syncthreads legal

  for (int kt = 0; kt < nkt; ++kt) {
    int kbase = kt * 32;
    f32x4 s[2];
#pragma unroll
    for (int half = 0; half < 2; ++half) {
      int c = kbase + half * 16 + l16;  // key token for this lane's score column
      bf16x8 kf0 = *(const bf16x8*)(kb + qkbase + (size_t)c * 64 + quad * 8);
      bf16x8 kf1 = *(const bf16x8*)(kb + qkbase + (size_t)c * 64 + 32 + quad * 8);
      f32x4 z = {};
      z = __builtin_amdgcn_mfma_f32_16x16x32_bf16(qf0, kf0, z, 0, 0, 0);
      z = __builtin_amdgcn_mfma_f32_16x16x32_bf16(qf1, kf1, z, 0, 0, 0);
#pragma unroll
      for (int r = 0; r < 4; ++r) {
        int rr = qrow0 + quad * 4 + r;
        if (c > rr) z[r] = -1e9f;  // exact ref masked value
      }
      s[half] = z;
    }
#pragma unroll
    for (int r = 0; r < 4; ++r) {
      float mt = fmaxf(s[0][r], s[1][r]);
      mt = fmaxf(mt, __shfl_xor(mt, 1));
      mt = fmaxf(mt, __shfl_xor(mt, 2));
      mt = fmaxf(mt, __shfl_xor(mt, 4));
      mt = fmaxf(mt, __shfl_xor(mt, 8));
      float mn = fmaxf(m_s[r], mt);
      float al = __expf(m_s[r] - mn);
      float p0 = __expf(s[0][r] - mn);
      float p1 = __expf(s[1][r] - mn);
      float rs = p0 + p1;
      rs += __shfl_xor(rs, 1);
      rs += __shfl_xor(rs, 2);
      rs += __shfl_xor(rs, 4);
      rs += __shfl_xor(rs, 8);
      l_s[r] = l_s[r] * al + rs;
      m_s[r] = mn;
#pragma unroll
      for (int dt = 0; dt < 4; ++dt) o[dt][r] *= al;
      pl[w][quad * 4 + r][l16] = f2bf(p0);
      pl[w][quad * 4 + r][16 + l16] = f2bf(p1);
    }
    __syncthreads();  // C-layout writes -> A-layout reads (lgkm drain)
    bf16x8 pf = *(const bf16x8*)(&pl[w][l16][quad * 8]);
#pragma unroll
    for (int dt = 0; dt < 4; ++dt) {
      bf16x8 vf = *(const bf16x8*)(vtb + (size_t)(bh * 64 + dt * 16 + l16) * T + kbase + quad * 8);
      o[dt] = __builtin_amdgcn_mfma_f32_16x16x32_bf16(pf, vf, o[dt], 0, 0, 0);
    }
    __syncthreads();  // P reads done before next overwrite
  }

#pragma unroll
  for (int r = 0; r < 4; ++r) {
    float inv = 1.0f / l_s[r];
    int row = qrow0 + quad * 4 + r;
    size_t obase = ((size_t)b * T + row) * 1024 + h * 64;  // merge heads
#pragma unroll
    for (int dt = 0; dt < 4; ++dt)
      ao[obase + dt * 16 + l16] = f2bf(o[dt][r] * inv);
  }
}

// ---------- launch ----------
extern "C" void kernel_launch(void* const* d_in, const int* in_sizes, int n_in,
                              void* d_out, int out_size, void* d_ws, size_t ws_size,
                              hipStream_t stream) {
  const float* x      = (const float*)d_in[0];  // [2,2048,1024]
  const float* W_attn = (const float*)d_in[1];  // [1024,3072]
  const float* b_attn = (const float*)d_in[2];  // [3072]
  const float* W_proj = (const float*)d_in[3];  // [1024,1024]
  const float* b_proj = (const float*)d_in[4];  // [1024]
  float* out = (float*)d_out;                   // [2,2048,1024] fp32

  if (ws_size < 50331648u) return;  // need 48 MB scratch

  char* ws = (char*)d_ws;
  u16* xb  = (u16*)(ws);                  //  8 MB  x bf16 [4096][1024]
  u16* wat = (u16*)(ws + 8388608u);       //  6 MB  W_attn^T bf16 [3072][1024]
  u16* wpt = (u16*)(ws + 14680064u);      //  2 MB  W_proj^T bf16 [1024][1024]
  u16* qb  = (u16*)(ws + 16777216u);      //  8 MB  q bf16 [B,H,T,dh] (pre-scaled)
  u16* kb  = (u16*)(ws + 25165824u);      //  8 MB  k bf16 [B,H,T,dh]
  u16* vtb = (u16*)(ws + 33554432u);      //  8 MB  v^T bf16 [B,H,dh,T]
  u16* ao  = (u16*)(ws + 41943040u);      //  8 MB  attn out bf16 [4096][1024]

  // 1. convert inputs to bf16 (weights transposed for [N][K] GEMM layout)
  cvt_f32_bf16<<<4096, 256, 0, stream>>>(x, xb, 4194304 / 4);
  transpose_cvt<<<dim3(96, 32), 256, 0, stream>>>(W_attn, wat, 1024, 3072);
  transpose_cvt<<<dim3(32, 32), 256, 0, stream>>>(W_proj, wpt, 1024, 1024);

  // 2. QKV projection, scatter epilogue
  gemm_bt<0><<<dim3(24, 32), 256, 0, stream>>>(xb, wat, 1024, b_attn, nullptr, qb, kb, vtb);

  // 3. causal flash attention
  flash_attn<<<dim3(32, 32), 256, 0, stream>>>(qb, kb, vtb, ao);

  // 4. output projection (fp32 out + bias)
  gemm_bt<1><<<dim3(8, 32), 256, 0, stream>>>(ao, wpt, 1024, b_proj, out, nullptr, nullptr, nullptr);
}

// Round 2
// 384.117 us; speedup vs baseline: 1.0110x; 1.0110x over previous
//
#include <hip/hip_runtime.h>

typedef unsigned short u16;
typedef __bf16 bf16x8 __attribute__((ext_vector_type(8)));
typedef float f32x4 __attribute__((ext_vector_type(4)));
typedef u16 u16x4 __attribute__((ext_vector_type(4)));

// ---------- helpers ----------
__device__ __forceinline__ u16 f2bf(float f) {
  unsigned u = __float_as_uint(f);
  u += 0x7fffu + ((u >> 16) & 1u);   // round-to-nearest-even
  return (u16)(u >> 16);
}

__device__ __forceinline__ void gload16(const u16* g, u16* l) {
  // 16B per lane, LDS dest = wave-uniform base + lane*16
  __builtin_amdgcn_global_load_lds((__attribute__((address_space(1))) void*)g,
                                   (__attribute__((address_space(3))) void*)l,
                                   16, 0, 0);
}

// ---------- fp32 -> bf16 elementwise ----------
__global__ __launch_bounds__(256) void cvt_f32_bf16(const float* __restrict__ in,
                                                    u16* __restrict__ out, int n4) {
  int i = blockIdx.x * 256 + threadIdx.x;
  if (i >= n4) return;
  float4 v = ((const float4*)in)[i];
  u16x4 o = { f2bf(v.x), f2bf(v.y), f2bf(v.z), f2bf(v.w) };
  ((u16x4*)out)[i] = o;
}

// ---------- fp32 [R][C] -> bf16 [C][R] tiled transpose ----------
__global__ __launch_bounds__(256) void transpose_cvt(const float* __restrict__ in,
                                                     u16* __restrict__ out, int R, int C) {
  __shared__ float tile[32][33];
  int c0 = blockIdx.x * 32, r0 = blockIdx.y * 32;
  int tx = threadIdx.x & 31, ty = threadIdx.x >> 5;  // 32 x 8
#pragma unroll
  for (int i = 0; i < 32; i += 8)
    tile[ty + i][tx] = in[(size_t)(r0 + ty + i) * C + c0 + tx];
  __syncthreads();
#pragma unroll
  for (int i = 0; i < 32; i += 8)
    out[(size_t)(c0 + ty + i) * R + r0 + tx] = f2bf(tile[tx][ty + i]);
}

// ---------- 128x128 bf16 GEMM, B pre-transposed [N][K] ----------
// EPI==0: qkv epilogue (bias, q-scale, scatter to q/k/v_t).  EPI==1: proj (bias, fp32 out).
template <int EPI>
__global__ __launch_bounds__(256) void gemm_bt(const u16* __restrict__ A,
                                               const u16* __restrict__ Bt, int K,
                                               const float* __restrict__ bias,
                                               float* __restrict__ outF,
                                               u16* __restrict__ qb, u16* __restrict__ kb,
                                               u16* __restrict__ vtb) {
  __shared__ __align__(16) u16 As[128 * 32];
  __shared__ __align__(16) u16 Bs[128 * 32];
  const int tid = threadIdx.x;
  const int w = tid >> 6, lane = tid & 63, quad = lane >> 4, l16 = lane & 15;
  const int wm = w >> 1, wn = w & 1;
  const int tm = blockIdx.y * 128, tn = blockIdx.x * 128;

  f32x4 acc[4][4] = {};

  const int ra = lane >> 2;        // row within 16-row chunk
  const int ca = (lane & 3) * 8;   // k offset (elements)
  const u16* gA0 = A + (size_t)(tm + w * 16 + ra) * K + ca;
  const u16* gA1 = A + (size_t)(tm + (w + 4) * 16 + ra) * K + ca;
  const u16* gB0 = Bt + (size_t)(tn + w * 16 + ra) * K + ca;
  const u16* gB1 = Bt + (size_t)(tn + (w + 4) * 16 + ra) * K + ca;
  u16* lA0 = &As[(w * 16) * 32];
  u16* lA1 = &As[((w + 4) * 16) * 32];
  u16* lB0 = &Bs[(w * 16) * 32];
  u16* lB1 = &Bs[((w + 4) * 16) * 32];

  for (int k0 = 0; k0 < K; k0 += 32) {
    gload16(gA0 + k0, lA0);
    gload16(gA1 + k0, lA1);
    gload16(gB0 + k0, lB0);
    gload16(gB1 + k0, lB1);
    __syncthreads();  // drains vmcnt -> LDS staged
    bf16x8 af[4], bfr[4];
#pragma unroll
    for (int mt = 0; mt < 4; ++mt)
      af[mt] = *(const bf16x8*)&As[(wm * 64 + mt * 16 + l16) * 32 + quad * 8];
#pragma unroll
    for (int nt = 0; nt < 4; ++nt)
      bfr[nt] = *(const bf16x8*)&Bs[(wn * 64 + nt * 16 + l16) * 32 + quad * 8];
#pragma unroll
    for (int mt = 0; mt < 4; ++mt)
#pragma unroll
      for (int nt = 0; nt < 4; ++nt)
        acc[mt][nt] = __builtin_amdgcn_mfma_f32_16x16x32_bf16(af[mt], bfr[nt], acc[mt][nt], 0, 0, 0);
    __syncthreads();  // LDS reads done before next staging
  }

#pragma unroll
  for (int mt = 0; mt < 4; ++mt) {
#pragma unroll
    for (int nt = 0; nt < 4; ++nt) {
#pragma unroll
      for (int r = 0; r < 4; ++r) {
        int row = tm + wm * 64 + mt * 16 + quad * 4 + r;  // C/D: row=(lane>>4)*4+reg
        int col = tn + wn * 64 + nt * 16 + l16;           // C/D: col=lane&15
        float v = acc[mt][nt][r] + bias[col];
        if (EPI == 0) {
          int which = col >> 10, d = col & 1023, h = d >> 6, dd = d & 63;
          int b = row >> 11, t = row & 2047;
          int bh = (b << 4) + h;
          if (which == 0)
            qb[((size_t)bh * 2048 + t) * 64 + dd] = f2bf(v * 0.125f);  // fold 1/sqrt(64)
          else if (which == 1)
            kb[((size_t)bh * 2048 + t) * 64 + dd] = f2bf(v);
          else
            vtb[((size_t)bh * 64 + dd) * 2048 + t] = f2bf(v);  // V transposed [dh][T]
        } else {
          outF[(size_t)row * 1024 + col] = v;
        }
      }
    }
  }
}

// ---------- causal flash attention v2 ----------
// S^T via mfma(kf, qf): each lane owns ONE q-row (l16) and 8 key-scores.
// Row reductions: 7 VALU + 2 shfl (xor16, xor32). Per-wave LDS P bounce, NO barriers.
// Wave w of block handles q-stripe blockIdx.x*4+w (16 rows), own trip count.
__global__ __launch_bounds__(256) void flash_attn(const u16* __restrict__ qb,
                                                  const u16* __restrict__ kb,
                                                  const u16* __restrict__ vtb,
                                                  u16* __restrict__ ao) {
  const int T = 2048;
  int w = threadIdx.x >> 6, lane = threadIdx.x & 63;
  int quad = lane >> 4, l16 = lane & 15;
  int stripe = blockIdx.x * 4 + w;   // 0..127
  int bh = blockIdx.y;
  int b = bh >> 4, h = bh & 15;
  int qrow0 = stripe * 16;
  int qrow = qrow0 + l16;            // this lane's q-row
  const size_t kvbase = (size_t)bh * T * 64;

  bf16x8 qf0 = *(const bf16x8*)(qb + kvbase + (size_t)qrow * 64 + quad * 8);
  bf16x8 qf1 = *(const bf16x8*)(qb + kvbase + (size_t)qrow * 64 + 32 + quad * 8);

  float m = -1e30f, l = 0.f;
  f32x4 o[4] = {};                   // O^T: o[dt][r] = O[dh=dt*16+quad*4+r][qrow]

  __shared__ __align__(16) u16 pl[4][16][40];  // per-wave P^T tile [qrow16][key32 +8 pad]
  u16* prow = &pl[w][l16][0];

  int nkt = (stripe + 2) >> 1;       // ceil((stripe+1)*16 / 32)
  for (int kt = 0; kt < nkt; ++kt) {
    int kbase = kt * 32;
    // prefetch V^T fragments (independent of scores -> overlaps softmax)
    bf16x8 vf[4];
#pragma unroll
    for (int dt = 0; dt < 4; ++dt)
      vf[dt] = *(const bf16x8*)(vtb + kvbase + (size_t)(dt * 16 + l16) * T + kbase + quad * 8);

    // S^T: z[t][r] = score(key = kbase + t*16 + quad*4 + r, qrow = l16's row)
    f32x4 z[2];
#pragma unroll
    for (int t = 0; t < 2; ++t) {
      int key = kbase + t * 16 + l16;
      bf16x8 kf0 = *(const bf16x8*)(kb + kvbase + (size_t)key * 64 + quad * 8);
      bf16x8 kf1 = *(const bf16x8*)(kb + kvbase + (size_t)key * 64 + 32 + quad * 8);
      f32x4 zz = {};
      zz = __builtin_amdgcn_mfma_f32_16x16x32_bf16(kf0, qf0, zz, 0, 0, 0);
      zz = __builtin_amdgcn_mfma_f32_16x16x32_bf16(kf1, qf1, zz, 0, 0, 0);
      z[t] = zz;
    }
    // causal mask (exp underflows to exact 0, matching ref's -1e9 path)
#pragma unroll
    for (int t = 0; t < 2; ++t)
#pragma unroll
      for (int r = 0; r < 4; ++r) {
        int key = kbase + t * 16 + quad * 4 + r;
        if (key > qrow) z[t][r] = -1e30f;
      }
    // row max: 7 VALU + 2 shfl
    float mloc = fmaxf(fmaxf(fmaxf(z[0][0], z[0][1]), fmaxf(z[0][2], z[0][3])),
                       fmaxf(fmaxf(z[1][0], z[1][1]), fmaxf(z[1][2], z[1][3])));
    mloc = fmaxf(mloc, __shfl_xor(mloc, 16));
    mloc = fmaxf(mloc, __shfl_xor(mloc, 32));
    float mn = fmaxf(m, mloc);
    float al = __expf(m - mn);
    m = mn;
    float p[8];
    float rs = 0.f;
#pragma unroll
    for (int t = 0; t < 2; ++t)
#pragma unroll
      for (int r = 0; r < 4; ++r) {
        float e = __expf(z[t][r] - mn);
        p[t * 4 + r] = e;
        rs += e;
      }
    rs += __shfl_xor(rs, 16);
    rs += __shfl_xor(rs, 32);
    l = l * al + rs;
    // rescale O^T by alpha (per-lane scalar: its q-row)
#pragma unroll
    for (int dt = 0; dt < 4; ++dt)
#pragma unroll
      for (int r = 0; r < 4; ++r) o[dt][r] *= al;
    // write P^T row: [l16][t*16 + quad*4 .. +3], packed b64 writes
    u16x4 pk0 = { f2bf(p[0]), f2bf(p[1]), f2bf(p[2]), f2bf(p[3]) };
    u16x4 pk1 = { f2bf(p[4]), f2bf(p[5]), f2bf(p[6]), f2bf(p[7]) };
    *(u16x4*)(prow + quad * 4) = pk0;
    *(u16x4*)(prow + 16 + quad * 4) = pk1;
    // same-wave DS ordering: drain lgkm, no block barrier needed (pl is wave-private)
    __asm__ __volatile__("s_waitcnt lgkmcnt(0)" ::: "memory");
    bf16x8 pf = *(const bf16x8*)(prow + quad * 8);  // B-frag: P^T[qrow=l16][k=quad*8+j]
#pragma unroll
    for (int dt = 0; dt < 4; ++dt)
      o[dt] = __builtin_amdgcn_mfma_f32_16x16x32_bf16(vf[dt], pf, o[dt], 0, 0, 0);
  }

  // epilogue: O^T col=l16 is this lane's q-row; rows quad*4+r are dh -> packed stores
  float inv = 1.0f / l;
  size_t obase = ((size_t)b * T + qrow) * 1024 + h * 64;
#pragma unroll
  for (int dt = 0; dt < 4; ++dt) {
    u16x4 ov = { f2bf(o[dt][0] * inv), f2bf(o[dt][1] * inv),
                 f2bf(o[dt][2] * inv), f2bf(o[dt][3] * inv) };
    *(u16x4*)(ao + obase + dt * 16 + quad * 4) = ov;
  }
}

// ---------- launch ----------
extern "C" void kernel_launch(void* const* d_in, const int* in_sizes, int n_in,
                              void* d_out, int out_size, void* d_ws, size_t ws_size,
                              hipStream_t stream) {
  const float* x      = (const float*)d_in[0];  // [2,2048,1024]
  const float* W_attn = (const float*)d_in[1];  // [1024,3072]
  const float* b_attn = (const float*)d_in[2];  // [3072]
  const float* W_proj = (const float*)d_in[3];  // [1024,1024]
  const float* b_proj = (const float*)d_in[4];  // [1024]
  float* out = (float*)d_out;                   // [2,2048,1024] fp32

  if (ws_size < 50331648u) return;  // need 48 MB scratch

  char* ws = (char*)d_ws;
  u16* xb  = (u16*)(ws);                  //  8 MB  x bf16 [4096][1024]
  u16* wat = (u16*)(ws + 8388608u);       //  6 MB  W_attn^T bf16 [3072][1024]
  u16* wpt = (u16*)(ws + 14680064u);      //  2 MB  W_proj^T bf16 [1024][1024]
  u16* qb  = (u16*)(ws + 16777216u);      //  8 MB  q bf16 [B,H,T,dh] (pre-scaled)
  u16* kb  = (u16*)(ws + 25165824u);      //  8 MB  k bf16 [B,H,T,dh]
  u16* vtb = (u16*)(ws + 33554432u);      //  8 MB  v^T bf16 [B,H,dh,T]
  u16* ao  = (u16*)(ws + 41943040u);      //  8 MB  attn out bf16 [4096][1024]

  // 1. convert inputs to bf16 (weights transposed for [N][K] GEMM layout)
  cvt_f32_bf16<<<4096, 256, 0, stream>>>(x, xb, 4194304 / 4);
  transpose_cvt<<<dim3(96, 32), 256, 0, stream>>>(W_attn, wat, 1024, 3072);
  transpose_cvt<<<dim3(32, 32), 256, 0, stream>>>(W_proj, wpt, 1024, 1024);

  // 2. QKV projection, scatter epilogue
  gemm_bt<0><<<dim3(24, 32), 256, 0, stream>>>(xb, wat, 1024, b_attn, nullptr, qb, kb, vtb);

  // 3. causal flash attention
  flash_attn<<<dim3(32, 32), 256, 0, stream>>>(qb, kb, vtb, ao);

  // 4. output projection (fp32 out + bias)
  gemm_bt<1><<<dim3(8, 32), 256, 0, stream>>>(ao, wpt, 1024, b_proj, out, nullptr, nullptr, nullptr);
}

// Round 4
// 274.064 us; speedup vs baseline: 1.4170x; 1.4016x over previous
//
#include <hip/hip_runtime.h>

typedef unsigned short u16;
typedef __bf16 bf16x8 __attribute__((ext_vector_type(8)));
typedef float f32x4 __attribute__((ext_vector_type(4)));
typedef u16 u16x4 __attribute__((ext_vector_type(4)));

// ---------- helpers ----------
__device__ __forceinline__ u16 f2bf(float f) {
  unsigned u = __float_as_uint(f);
  u += 0x7fffu + ((u >> 16) & 1u);   // round-to-nearest-even
  return (u16)(u >> 16);
}

__device__ __forceinline__ float fast_exp2(float x) {
  return __builtin_amdgcn_exp2f(x);  // raw v_exp_f32
}

__device__ __forceinline__ void gload16(const u16* g, u16* l) {
  __builtin_amdgcn_global_load_lds((__attribute__((address_space(1))) void*)g,
                                   (__attribute__((address_space(3))) void*)l,
                                   16, 0, 0);
}

// ---------- fp32 -> bf16 elementwise ----------
__global__ __launch_bounds__(256) void cvt_f32_bf16(const float* __restrict__ in,
                                                    u16* __restrict__ out, int n4) {
  int i = blockIdx.x * 256 + threadIdx.x;
  if (i >= n4) return;
  float4 v = ((const float4*)in)[i];
  u16x4 o = { f2bf(v.x), f2bf(v.y), f2bf(v.z), f2bf(v.w) };
  ((u16x4*)out)[i] = o;
}

// ---------- fp32 [R][C] -> bf16 [C][R] tiled transpose ----------
__global__ __launch_bounds__(256) void transpose_cvt(const float* __restrict__ in,
                                                     u16* __restrict__ out, int R, int C) {
  __shared__ float tile[32][33];
  int c0 = blockIdx.x * 32, r0 = blockIdx.y * 32;
  int tx = threadIdx.x & 31, ty = threadIdx.x >> 5;  // 32 x 8
#pragma unroll
  for (int i = 0; i < 32; i += 8)
    tile[ty + i][tx] = in[(size_t)(r0 + ty + i) * C + c0 + tx];
  __syncthreads();
#pragma unroll
  for (int i = 0; i < 32; i += 8)
    out[(size_t)(c0 + ty + i) * R + r0 + tx] = f2bf(tile[tx][ty + i]);
}

// ---------- 128x128 bf16 GEMM, B pre-transposed [N][K] ----------
template <int EPI>
__global__ __launch_bounds__(256) void gemm_bt(const u16* __restrict__ A,
                                               const u16* __restrict__ Bt, int K,
                                               const float* __restrict__ bias,
                                               float* __restrict__ outF,
                                               u16* __restrict__ qb, u16* __restrict__ kb,
                                               u16* __restrict__ vtb) {
  __shared__ __align__(16) u16 As[128 * 32];
  __shared__ __align__(16) u16 Bs[128 * 32];
  const int tid = threadIdx.x;
  const int w = tid >> 6, lane = tid & 63, quad = lane >> 4, l16 = lane & 15;
  const int wm = w >> 1, wn = w & 1;
  const int tm = blockIdx.y * 128, tn = blockIdx.x * 128;

  f32x4 acc[4][4] = {};

  const int ra = lane >> 2;
  const int ca = (lane & 3) * 8;
  const u16* gA0 = A + (size_t)(tm + w * 16 + ra) * K + ca;
  const u16* gA1 = A + (size_t)(tm + (w + 4) * 16 + ra) * K + ca;
  const u16* gB0 = Bt + (size_t)(tn + w * 16 + ra) * K + ca;
  const u16* gB1 = Bt + (size_t)(tn + (w + 4) * 16 + ra) * K + ca;
  u16* lA0 = &As[(w * 16) * 32];
  u16* lA1 = &As[((w + 4) * 16) * 32];
  u16* lB0 = &Bs[(w * 16) * 32];
  u16* lB1 = &Bs[((w + 4) * 16) * 32];

  for (int k0 = 0; k0 < K; k0 += 32) {
    gload16(gA0 + k0, lA0);
    gload16(gA1 + k0, lA1);
    gload16(gB0 + k0, lB0);
    gload16(gB1 + k0, lB1);
    __syncthreads();
    bf16x8 af[4], bfr[4];
#pragma unroll
    for (int mt = 0; mt < 4; ++mt)
      af[mt] = *(const bf16x8*)&As[(wm * 64 + mt * 16 + l16) * 32 + quad * 8];
#pragma unroll
    for (int nt = 0; nt < 4; ++nt)
      bfr[nt] = *(const bf16x8*)&Bs[(wn * 64 + nt * 16 + l16) * 32 + quad * 8];
#pragma unroll
    for (int mt = 0; mt < 4; ++mt)
#pragma unroll
      for (int nt = 0; nt < 4; ++nt)
        acc[mt][nt] = __builtin_amdgcn_mfma_f32_16x16x32_bf16(af[mt], bfr[nt], acc[mt][nt], 0, 0, 0);
    __syncthreads();
  }

#pragma unroll
  for (int mt = 0; mt < 4; ++mt) {
#pragma unroll
    for (int nt = 0; nt < 4; ++nt) {
#pragma unroll
      for (int r = 0; r < 4; ++r) {
        int row = tm + wm * 64 + mt * 16 + quad * 4 + r;
        int col = tn + wn * 64 + nt * 16 + l16;
        float v = acc[mt][nt][r] + bias[col];
        if (EPI == 0) {
          int which = col >> 10, d = col & 1023, h = d >> 6, dd = d & 63;
          int b = row >> 11, t = row & 2047;
          int bh = (b << 4) + h;
          if (which == 0)
            qb[((size_t)bh * 2048 + t) * 64 + dd] = f2bf(v * 0.18033688f);  // 1/8 * log2(e)
          else if (which == 1)
            kb[((size_t)bh * 2048 + t) * 64 + dd] = f2bf(v);
          else
            vtb[((size_t)bh * 64 + dd) * 2048 + t] = f2bf(v);
        } else {
          outF[(size_t)row * 1024 + col] = v;
        }
      }
    }
  }
}

// softmax update for one stripe's 32-key score tile (exp2 domain).
// z0/z1: S^T tiles (key = kbase + {0,16} + quad*4 + r, q-row = l16's row).
__device__ __forceinline__ void sm_update(f32x4 z0, f32x4 z1, int kbase, int quad,
                                          int qrow, float& m, float& l, f32x4* o,
                                          u16* prow) {
  int k0 = kbase + quad * 4;
#pragma unroll
  for (int r = 0; r < 4; ++r) {
    if (k0 + r > qrow) z0[r] = -1e30f;
    if (k0 + 16 + r > qrow) z1[r] = -1e30f;
  }
  float mloc = fmaxf(fmaxf(fmaxf(z0[0], z0[1]), fmaxf(z0[2], z0[3])),
                     fmaxf(fmaxf(z1[0], z1[1]), fmaxf(z1[2], z1[3])));
  mloc = fmaxf(mloc, __shfl_xor(mloc, 16));
  mloc = fmaxf(mloc, __shfl_xor(mloc, 32));
  float mn = fmaxf(m, mloc);
  float al = fast_exp2(m - mn);
  m = mn;
  float p[8];
  float rs = 0.f;
#pragma unroll
  for (int r = 0; r < 4; ++r) {
    p[r] = fast_exp2(z0[r] - mn);
    p[4 + r] = fast_exp2(z1[r] - mn);
    rs += p[r] + p[4 + r];
  }
  rs += __shfl_xor(rs, 16);
  rs += __shfl_xor(rs, 32);
  l = l * al + rs;
#pragma unroll
  for (int dt = 0; dt < 4; ++dt)
#pragma unroll
    for (int r = 0; r < 4; ++r) o[dt][r] *= al;
  u16x4 pk0 = { f2bf(p[0]), f2bf(p[1]), f2bf(p[2]), f2bf(p[3]) };
  u16x4 pk1 = { f2bf(p[4]), f2bf(p[5]), f2bf(p[6]), f2bf(p[7]) };
  *(u16x4*)(prow + quad * 4) = pk0;
  *(u16x4*)(prow + 16 + quad * 4) = pk1;
}

// ---------- causal flash attention v3: paired stripes, shared K/V tiles ----------
// Wave handles stripes sA = bx*4+w (light) and sB = 127-sA (heavy) INTERLEAVED
// over the same key tiles (A's key range is a prefix of B's). K/V loaded once per
// tile, K register-double-buffered. Per-wave compute is ~constant -> balanced.
__global__ __launch_bounds__(256) void flash_attn(const u16* __restrict__ qb,
                                                  const u16* __restrict__ kb,
                                                  const u16* __restrict__ vtb,
                                                  u16* __restrict__ ao) {
  const int T = 2048;
  int w = threadIdx.x >> 6, lane = threadIdx.x & 63;
  int quad = lane >> 4, l16 = lane & 15;
  int sA = blockIdx.x * 4 + w;       // 0..63
  int sB = 127 - sA;                 // 64..127
  int bh = blockIdx.y;
  int b = bh >> 4, h = bh & 15;
  int qrowA = sA * 16 + l16, qrowB = sB * 16 + l16;
  const size_t kvbase = (size_t)bh * T * 64;

  bf16x8 qA0 = *(const bf16x8*)(qb + kvbase + (size_t)qrowA * 64 + quad * 8);
  bf16x8 qA1 = *(const bf16x8*)(qb + kvbase + (size_t)qrowA * 64 + 32 + quad * 8);
  bf16x8 qB0 = *(const bf16x8*)(qb + kvbase + (size_t)qrowB * 64 + quad * 8);
  bf16x8 qB1 = *(const bf16x8*)(qb + kvbase + (size_t)qrowB * 64 + 32 + quad * 8);

  float mA = -1e30f, lA = 0.f, mB = -1e30f, lB = 0.f;
  f32x4 oA[4] = {}, oB[4] = {};

  __shared__ __align__(16) u16 pl[4][2][16][36];  // per-wave P^T tiles, stride 36
  u16* prowA = &pl[w][0][l16][0];
  u16* prowB = &pl[w][1][l16][0];

  const int nktA = (sA + 2) >> 1;
  const int nktB = (sB + 2) >> 1;

  const u16* kfb = kb + kvbase + (size_t)l16 * 64 + quad * 8;
  const u16* vfb = vtb + kvbase + (size_t)l16 * T + quad * 8;

  bf16x8 kc[4];  // current K tile: [t*2 + dh-half], t = key 16-group
  kc[0] = *(const bf16x8*)(kfb);
  kc[1] = *(const bf16x8*)(kfb + 32);
  kc[2] = *(const bf16x8*)(kfb + 1024);
  kc[3] = *(const bf16x8*)(kfb + 1024 + 32);

  for (int kt = 0; kt < nktB; ++kt) {
    const int kbase = kt * 32;
    // current V (used at iteration end; latency overlaps QK+softmax)
    bf16x8 vc[4];
#pragma unroll
    for (int dt = 0; dt < 4; ++dt)
      vc[dt] = *(const bf16x8*)(vfb + (size_t)dt * (16 * 2048) + kbase);
    // prefetch next K tile (in flight across this iteration's LDS drain)
    bf16x8 kn[4];
    const bool more = (kt + 1 < nktB);
    if (more) {
      const u16* knp = kfb + (size_t)(kbase + 32) * 64;
      kn[0] = *(const bf16x8*)(knp);
      kn[1] = *(const bf16x8*)(knp + 32);
      kn[2] = *(const bf16x8*)(knp + 1024);
      kn[3] = *(const bf16x8*)(knp + 1024 + 32);
    }
    const bool doA = (kt < nktA);

    // QK^T (S^T layout: C col = q-row = l16, C row = key = quad*4+r)
    f32x4 zB0 = {}, zB1 = {};
    zB0 = __builtin_amdgcn_mfma_f32_16x16x32_bf16(kc[0], qB0, zB0, 0, 0, 0);
    zB0 = __builtin_amdgcn_mfma_f32_16x16x32_bf16(kc[1], qB1, zB0, 0, 0, 0);
    zB1 = __builtin_amdgcn_mfma_f32_16x16x32_bf16(kc[2], qB0, zB1, 0, 0, 0);
    zB1 = __builtin_amdgcn_mfma_f32_16x16x32_bf16(kc[3], qB1, zB1, 0, 0, 0);
    f32x4 zA0 = {}, zA1 = {};
    if (doA) {
      zA0 = __builtin_amdgcn_mfma_f32_16x16x32_bf16(kc[0], qA0, zA0, 0, 0, 0);
      zA0 = __builtin_amdgcn_mfma_f32_16x16x32_bf16(kc[1], qA1, zA0, 0, 0, 0);
      zA1 = __builtin_amdgcn_mfma_f32_16x16x32_bf16(kc[2], qA0, zA1, 0, 0, 0);
      zA1 = __builtin_amdgcn_mfma_f32_16x16x32_bf16(kc[3], qA1, zA1, 0, 0, 0);
    }

    sm_update(zB0, zB1, kbase, quad, qrowB, mB, lB, oB, prowB);
    if (doA) sm_update(zA0, zA1, kbase, quad, qrowA, mA, lA, oA, prowA);

    // wave-private LDS: drain ds ops, no block barrier needed
    __asm__ __volatile__("s_waitcnt lgkmcnt(0)" ::: "memory");

    bf16x8 pfB = *(const bf16x8*)(prowB + quad * 8);
#pragma unroll
    for (int dt = 0; dt < 4; ++dt)
      oB[dt] = __builtin_amdgcn_mfma_f32_16x16x32_bf16(vc[dt], pfB, oB[dt], 0, 0, 0);
    if (doA) {
      bf16x8 pfA = *(const bf16x8*)(prowA + quad * 8);
#pragma unroll
      for (int dt = 0; dt < 4; ++dt)
        oA[dt] = __builtin_amdgcn_mfma_f32_16x16x32_bf16(vc[dt], pfA, oA[dt], 0, 0, 0);
    }
#pragma unroll
    for (int i = 0; i < 4; ++i) kc[i] = kn[i];
  }

  // epilogue: O^T col = q-row (l16); rows quad*4+r = dh -> packed stores
  {
    float inv = 1.0f / lA;
    size_t obase = ((size_t)b * T + qrowA) * 1024 + h * 64;
#pragma unroll
    for (int dt = 0; dt < 4; ++dt) {
      u16x4 ov = { f2bf(oA[dt][0] * inv), f2bf(oA[dt][1] * inv),
                   f2bf(oA[dt][2] * inv), f2bf(oA[dt][3] * inv) };
      *(u16x4*)(ao + obase + dt * 16 + quad * 4) = ov;
    }
  }
  {
    float inv = 1.0f / lB;
    size_t obase = ((size_t)b * T + qrowB) * 1024 + h * 64;
#pragma unroll
    for (int dt = 0; dt < 4; ++dt) {
      u16x4 ov = { f2bf(oB[dt][0] * inv), f2bf(oB[dt][1] * inv),
                   f2bf(oB[dt][2] * inv), f2bf(oB[dt][3] * inv) };
      *(u16x4*)(ao + obase + dt * 16 + quad * 4) = ov;
    }
  }
}

// ---------- launch ----------
extern "C" void kernel_launch(void* const* d_in, const int* in_sizes, int n_in,
                              void* d_out, int out_size, void* d_ws, size_t ws_size,
                              hipStream_t stream) {
  const float* x      = (const float*)d_in[0];
  const float* W_attn = (const float*)d_in[1];
  const float* b_attn = (const float*)d_in[2];
  const float* W_proj = (const float*)d_in[3];
  const float* b_proj = (const float*)d_in[4];
  float* out = (float*)d_out;

  if (ws_size < 50331648u) return;

  char* ws = (char*)d_ws;
  u16* xb  = (u16*)(ws);
  u16* wat = (u16*)(ws + 8388608u);
  u16* wpt = (u16*)(ws + 14680064u);
  u16* qb  = (u16*)(ws + 16777216u);   // q bf16, pre-scaled by log2(e)/8
  u16* kb  = (u16*)(ws + 25165824u);
  u16* vtb = (u16*)(ws + 33554432u);
  u16* ao  = (u16*)(ws + 41943040u);

  cvt_f32_bf16<<<4096, 256, 0, stream>>>(x, xb, 4194304 / 4);
  transpose_cvt<<<dim3(96, 32), 256, 0, stream>>>(W_attn, wat, 1024, 3072);
  transpose_cvt<<<dim3(32, 32), 256, 0, stream>>>(W_proj, wpt, 1024, 1024);

  gemm_bt<0><<<dim3(24, 32), 256, 0, stream>>>(xb, wat, 1024, b_attn, nullptr, qb, kb, vtb);

  flash_attn<<<dim3(16, 32), 256, 0, stream>>>(qb, kb, vtb, ao);

  gemm_bt<1><<<dim3(8, 32), 256, 0, stream>>>(ao, wpt, 1024, b_proj, out, nullptr, nullptr, nullptr);
}